// Round 2
// baseline (309.653 us; speedup 1.0000x reference)
//
#include <hip/hip_runtime.h>
#include <math.h>

// Problem constants (fixed by the reference)
constexpr int kEmb    = 128;
constexpr int kRegion = 7;
constexpr int kRadius = 3;
constexpr int kBatch  = 32;
constexpr int kSeq    = 1024;

// Tiling: T output positions per block, staged halo of 2*RADIUS tokens.
constexpr int T  = 16;
constexpr int NT = T + 2 * kRadius;               // 22 staged token blocks
constexpr int kBlockFloats = kRegion * kEmb;      // 896 floats = 3584 B per token
constexpr int kQuads  = kBlockFloats / 4;         // 224 float4 per token block
constexpr int kStride = kBlockFloats + 4;         // 900: +4 pad (16B-aligned, shifts banks)

// h[b,s,e] = max_r U_full[win*7+r][e] * W_full[t][e]
//   W_full[t]     = (t > 0) ? W[t-1]         : 0
//   U_full[t*7+r] = (t > 0) ? U[(t-1)*7 + r] : 0   (covers padding AND token 0)
//
// Structure: for token at seq position p, the 7 rows it ever contributes are
// U[(t-1)*7 + 0..6] — one contiguous 3.5 KB block. Stage per-token blocks in
// LDS (contiguous global reads), then outputs read their 7 rows from LDS.
__global__ __launch_bounds__(256, 2) void region_encoder_kernel(
    const int*   __restrict__ seq,   // (32, 1024)
    const float* __restrict__ W,     // (49999, 128)
    const float* __restrict__ U,     // (349993, 128)
    float*       __restrict__ out)   // (32, 1024, 128)
{
    __shared__ float lds[NT * kStride];           // 79,200 B -> 2 blocks/CU

    const int tile = blockIdx.x;                  // 0 .. 32*64-1
    const int b    = tile >> 6;                   // kSeq/T == 64
    const int s0   = (tile & 63) * T;

    // ---- stage NT contiguous token blocks (3.5 KB each) into LDS ----
    for (int k = threadIdx.x; k < NT * kQuads; k += 256) {
        const int j = k / kQuads;                 // token slot 0..21 (const div)
        const int q = k - j * kQuads;             // quad within block 0..223
        const int p = s0 - kRadius + j;           // seq position of this token
        int t = 0;
        if (p >= 0 && p < kSeq) t = seq[b * kSeq + p];
        float4 v = make_float4(0.f, 0.f, 0.f, 0.f);
        if (t > 0) {
            v = ((const float4*)(U + (size_t)(t - 1) * kBlockFloats))[q];
        }
        *(float4*)&lds[j * kStride + q * 4] = v;
    }
    __syncthreads();

    // ---- compute T output positions: 32 lanes/position, 8 groups/block ----
    const int lane = threadIdx.x & 31;
    const int grp  = threadIdx.x >> 5;

    for (int i = grp; i < T; i += 8) {
        const int s   = s0 + i;
        const int pos = b * kSeq + s;

        const int t = seq[pos];                   // L1-resident by now
        float4 wv = make_float4(0.f, 0.f, 0.f, 0.f);
        if (t > 0) {
            wv = ((const float4*)(W + (size_t)(t - 1) * kEmb))[lane];
        }

        // output s, offset r  ->  LDS slot (i + r), row r
        float4 u0 = *(const float4*)&lds[(i + 0) * kStride + 0 * kEmb + lane * 4];
        float4 m;
        m.x = u0.x * wv.x;
        m.y = u0.y * wv.y;
        m.z = u0.z * wv.z;
        m.w = u0.w * wv.w;
#pragma unroll
        for (int r = 1; r < kRegion; ++r) {
            float4 u = *(const float4*)&lds[(i + r) * kStride + r * kEmb + lane * 4];
            m.x = fmaxf(m.x, u.x * wv.x);
            m.y = fmaxf(m.y, u.y * wv.y);
            m.z = fmaxf(m.z, u.z * wv.z);
            m.w = fmaxf(m.w, u.w * wv.w);
        }

        ((float4*)out)[(size_t)pos * (kEmb / 4) + lane] = m;
    }
}

extern "C" void kernel_launch(void* const* d_in, const int* in_sizes, int n_in,
                              void* d_out, int out_size, void* d_ws, size_t ws_size,
                              hipStream_t stream) {
    const int*   seq = (const int*)d_in[0];
    const float* W   = (const float*)d_in[1];
    const float* U   = (const float*)d_in[2];
    float*       out = (float*)d_out;

    const int blocks = kBatch * (kSeq / T);       // 2048
    region_encoder_kernel<<<dim3(blocks), dim3(256), 0, stream>>>(seq, W, U, out);
}

// Round 3
// 252.251 us; speedup vs baseline: 1.2276x; 1.2276x over previous
//
#include <hip/hip_runtime.h>
#include <math.h>

// Problem constants (fixed by the reference)
constexpr int kEmb    = 128;
constexpr int kRegion = 7;
constexpr int kRadius = 3;
constexpr int kBatch  = 32;
constexpr int kSeq    = 1024;
constexpr int kPos    = kBatch * kSeq;

// h[b,s,e] = max_r U_full[win*7+r][e] * W_full[t][e]
//   W_full[t]     = (t > 0) ? W[t-1]         : 0
//   U_full[t*7+r] = (t > 0) ? U[(t-1)*7 + r] : 0   (covers padding AND token 0)
//
// Wave64 covers two ADJACENT outputs (sE, sE+1). For interior window blocks
// p = sE-2..sE+3, output sE needs row r = p-sE+3 and output sE+1 needs row
// r-1 of the SAME token block -> rows (r-1, r) are one contiguous 1 KB chunk.
// Load it with the full wave (1 segment instead of 2 scattered 512 B ones),
// then swap halves in-register: lanes 0-31 loaded row r-1 but need row r
// (and vice versa) -> __shfl(lane^32). Edge blocks (p=sE-3 row 0 for sE,
// p=sE+4 row 6 for sE+1) share one split load, no swap needed.
__global__ __launch_bounds__(256) void region_encoder_kernel(
    const int*   __restrict__ seq,   // (32, 1024)
    const float* __restrict__ W,     // (49999, 128)
    const float* __restrict__ U,     // (349993, 128)
    float*       __restrict__ out)   // (32, 1024, 128)
{
    const int lane64 = threadIdx.x & 63;
    const int half   = lane64 >> 5;          // 0 -> output sE, 1 -> output sE+1
    const int lane32 = lane64 & 31;
    const int wid    = threadIdx.x >> 6;     // wave id in block, 0..3
    const int pairE  = blockIdx.x * 4 + wid; // global even-pair index
    const int b      = pairE >> 9;           // 512 pairs per batch row
    const int sE     = (pairE & 511) * 2;
    const int s      = sE + half;
    const int pos    = b * kSeq + s;

    // ---- tokens for window blocks p = sE-3 .. sE+4 (L1-broadcast reads) ----
    int tok[8];
#pragma unroll
    for (int j = 0; j < 8; ++j) {
        const int p = sE - 3 + j;
        tok[j] = (p >= 0 && p < kSeq) ? seq[b * kSeq + p] : 0;
    }

    // ---- W row for own position ----
    const int t = tok[3 + half];
    float4 wv = make_float4(0.f, 0.f, 0.f, 0.f);
    if (t > 0) wv = ((const float4*)(W + (size_t)(t - 1) * kEmb))[lane32];

    // ---- edge load: half 0 -> block sE-3 row 0 ; half 1 -> block sE+4 row 6
    const int tE = half ? tok[7] : tok[0];
    float4 uEdge = make_float4(0.f, 0.f, 0.f, 0.f);
    if (tE > 0) {
        const size_t q = (size_t)(tE - 1) * (kRegion * kEmb / 4)
                       + (half ? 6 * (kEmb / 4) : 0) + lane32;
        uEdge = ((const float4*)U)[q];
    }

    // ---- interior blocks j=1..6 (p = sE-3+j): contiguous rows (j-1, j) ----
    float4 uIn[6];
#pragma unroll
    for (int j = 1; j <= 6; ++j) {
        const int tp = tok[j];               // wave-uniform
        float4 v = make_float4(0.f, 0.f, 0.f, 0.f);
        if (tp > 0) {
            const size_t q = (size_t)(tp - 1) * (kRegion * kEmb / 4)
                           + (size_t)(j - 1) * (kEmb / 4) + lane64;
            v = ((const float4*)U)[q];       // full-wave contiguous 1 KB
        }
        uIn[j - 1] = v;
    }

    // ---- swap halves: lane l <-> lane l^32 (rows r-1 <-> r) ----
    const int src = lane64 ^ 32;
#pragma unroll
    for (int j = 0; j < 6; ++j) {
        float4 v = uIn[j];
        v.x = __shfl(v.x, src, 64);
        v.y = __shfl(v.y, src, 64);
        v.z = __shfl(v.z, src, 64);
        v.w = __shfl(v.w, src, 64);
        uIn[j] = v;
    }

    // ---- max over the 7 rows (edge + 6 interior) ----
    float4 m;
    m.x = uEdge.x * wv.x;
    m.y = uEdge.y * wv.y;
    m.z = uEdge.z * wv.z;
    m.w = uEdge.w * wv.w;
#pragma unroll
    for (int j = 0; j < 6; ++j) {
        m.x = fmaxf(m.x, uIn[j].x * wv.x);
        m.y = fmaxf(m.y, uIn[j].y * wv.y);
        m.z = fmaxf(m.z, uIn[j].z * wv.z);
        m.w = fmaxf(m.w, uIn[j].w * wv.w);
    }

    ((float4*)out)[(size_t)pos * (kEmb / 4) + lane32] = m;
}

extern "C" void kernel_launch(void* const* d_in, const int* in_sizes, int n_in,
                              void* d_out, int out_size, void* d_ws, size_t ws_size,
                              hipStream_t stream) {
    const int*   seq = (const int*)d_in[0];
    const float* W   = (const float*)d_in[1];
    const float* U   = (const float*)d_in[2];
    float*       out = (float*)d_out;

    const int blocks = kPos / 8;             // 4096 blocks, 8 positions each
    region_encoder_kernel<<<dim3(blocks), dim3(256), 0, stream>>>(seq, W, U, out);
}

// Round 5
// 250.523 us; speedup vs baseline: 1.2360x; 1.0069x over previous
//
#include <hip/hip_runtime.h>
#include <math.h>

// Problem constants (fixed by the reference)
constexpr int kEmb    = 128;
constexpr int kRegion = 7;
constexpr int kRadius = 3;
constexpr int kBatch  = 32;
constexpr int kSeq    = 1024;
constexpr int kPos    = kBatch * kSeq;
constexpr int kHalf   = kPos / 2;        // 16384

typedef float f32x4 __attribute__((ext_vector_type(4)));  // native vec for NT store

// h[b,s,e] = max_r U_full[win*7+r][e] * W_full[t][e]
//   W_full[t]     = (t > 0) ? W[t-1]         : 0
//   U_full[t*7+r] = (t > 0) ? U[(t-1)*7 + r] : 0   (covers padding AND token 0)
//
// R4: software-pipeline TWO positions per 32-lane group (p and p+kPos/2).
// All token loads for both positions issue up front; both positions' U/W
// loads then issue as soon as tokens land -> the two ~900-cycle gather
// epochs overlap instead of serializing. Out-stores are nontemporal (output
// is never re-read; keep L2 for U).
__global__ __launch_bounds__(256) void region_encoder_kernel(
    const int*   __restrict__ seq,   // (32, 1024)
    const float* __restrict__ W,     // (49999, 128)
    const float* __restrict__ U,     // (349993, 128)
    float*       __restrict__ out)   // (32, 1024, 128)
{
    const int lane = threadIdx.x & 31;
    const int grp  = threadIdx.x >> 5;           // 0..7
    const int p0   = blockIdx.x * 8 + grp;       // 0 .. kHalf-1
    const int p1   = p0 + kHalf;
    const int b0   = p0 >> 10, s0 = p0 & (kSeq - 1);
    const int b1   = p1 >> 10, s1 = p1 & (kSeq - 1);

    // ---- all token loads for BOTH positions, issued together ----
    int tok0[kRegion], tok1[kRegion];
#pragma unroll
    for (int r = 0; r < kRegion; ++r) {
        const int sp0 = s0 + r - kRadius;
        tok0[r] = (sp0 >= 0 && sp0 < kSeq) ? seq[b0 * kSeq + sp0] : 0;
        const int sp1 = s1 + r - kRadius;
        tok1[r] = (sp1 >= 0 && sp1 < kSeq) ? seq[b1 * kSeq + sp1] : 0;
    }

    // ---- W rows for both center tokens ----
    const int t0 = tok0[kRadius];
    const int t1 = tok1[kRadius];
    float4 wv0 = make_float4(0.f, 0.f, 0.f, 0.f);
    float4 wv1 = make_float4(0.f, 0.f, 0.f, 0.f);
    if (t0 > 0) wv0 = ((const float4*)(W + (size_t)(t0 - 1) * kEmb))[lane];
    if (t1 > 0) wv1 = ((const float4*)(W + (size_t)(t1 - 1) * kEmb))[lane];

    // ---- all 14 U-row loads, issued together ----
    float4 uv0[kRegion], uv1[kRegion];
#pragma unroll
    for (int r = 0; r < kRegion; ++r) {
        uv0[r] = make_float4(0.f, 0.f, 0.f, 0.f);
        if (tok0[r] > 0) {
            const size_t row = (size_t)(tok0[r] - 1) * kRegion + r;
            uv0[r] = ((const float4*)(U + row * kEmb))[lane];
        }
    }
#pragma unroll
    for (int r = 0; r < kRegion; ++r) {
        uv1[r] = make_float4(0.f, 0.f, 0.f, 0.f);
        if (tok1[r] > 0) {
            const size_t row = (size_t)(tok1[r] - 1) * kRegion + r;
            uv1[r] = ((const float4*)(U + row * kEmb))[lane];
        }
    }

    // ---- consume position 0 ----
    float4 m0;
    m0.x = uv0[0].x * wv0.x;
    m0.y = uv0[0].y * wv0.y;
    m0.z = uv0[0].z * wv0.z;
    m0.w = uv0[0].w * wv0.w;
#pragma unroll
    for (int r = 1; r < kRegion; ++r) {
        m0.x = fmaxf(m0.x, uv0[r].x * wv0.x);
        m0.y = fmaxf(m0.y, uv0[r].y * wv0.y);
        m0.z = fmaxf(m0.z, uv0[r].z * wv0.z);
        m0.w = fmaxf(m0.w, uv0[r].w * wv0.w);
    }
    {
        f32x4 v = { m0.x, m0.y, m0.z, m0.w };
        __builtin_nontemporal_store(v, &((f32x4*)out)[(size_t)p0 * (kEmb / 4) + lane]);
    }

    // ---- consume position 1 ----
    float4 m1;
    m1.x = uv1[0].x * wv1.x;
    m1.y = uv1[0].y * wv1.y;
    m1.z = uv1[0].z * wv1.z;
    m1.w = uv1[0].w * wv1.w;
#pragma unroll
    for (int r = 1; r < kRegion; ++r) {
        m1.x = fmaxf(m1.x, uv1[r].x * wv1.x);
        m1.y = fmaxf(m1.y, uv1[r].y * wv1.y);
        m1.z = fmaxf(m1.z, uv1[r].z * wv1.z);
        m1.w = fmaxf(m1.w, uv1[r].w * wv1.w);
    }
    {
        f32x4 v = { m1.x, m1.y, m1.z, m1.w };
        __builtin_nontemporal_store(v, &((f32x4*)out)[(size_t)p1 * (kEmb / 4) + lane]);
    }
}

extern "C" void kernel_launch(void* const* d_in, const int* in_sizes, int n_in,
                              void* d_out, int out_size, void* d_ws, size_t ws_size,
                              hipStream_t stream) {
    const int*   seq = (const int*)d_in[0];
    const float* W   = (const float*)d_in[1];
    const float* U   = (const float*)d_in[2];
    float*       out = (float*)d_out;

    const int blocks = kHalf / 8;                // 2048 blocks, 16 positions each
    region_encoder_kernel<<<dim3(blocks), dim3(256), 0, stream>>>(seq, W, U, out);
}